// Round 8
// baseline (435.085 us; speedup 1.0000x reference)
//
#include <hip/hip_runtime.h>
#include <hip/hip_bf16.h>

#define HC1 512   // layer-1 heads*channels (4*128)
#define HC2 256   // layer-2 (1*256)
#define D_IN 256

typedef __hip_bfloat16  bf16;
typedef __hip_bfloat162 bf162;
typedef __attribute__((ext_vector_type(8))) short short8;   // 8 bf16 = 4 VGPR
typedef __attribute__((ext_vector_type(4))) float f32x4;

__device__ __forceinline__ void unpack8(short8 q, float* x) {
  union { short8 s; bf162 h[4]; } u; u.s = q;
#pragma unroll
  for (int j = 0; j < 4; j++) {
    x[2 * j]     = __bfloat162float(u.h[j].x);
    x[2 * j + 1] = __bfloat162float(u.h[j].y);
  }
}

// DPP-based partial-wave add: p += lane[p ^ pattern] without LDS pipe.
// 0xB1 = quad_perm[1,0,3,2] (xor1), 0x4E = quad_perm[2,3,0,1] (xor2),
// 0x124 = row_ror:4, 0x128 = row_ror:8 (within 16-lane rows).
template <int CTRL>
__device__ __forceinline__ float dppadd(float x) {
  union { float f; int i; } u, v;
  u.f = x;
  v.i = __builtin_amdgcn_update_dpp(0, u.i, CTRL, 0xF, 0xF, true);
  return x + v.f;
}
// sum over each 16-lane group (result in every lane of the group)
__device__ __forceinline__ float red16(float p) {
  p = dppadd<0xB1>(p);
  p = dppadd<0x4E>(p);
  p = dppadd<0x124>(p);
  p = dppadd<0x128>(p);
  return p;
}

// ------------------------- async global->LDS (16B/lane) --------------------
__device__ __forceinline__ void glds16(const bf16* g, bf16* l) {
#if __has_builtin(__builtin_amdgcn_global_load_lds)
  __builtin_amdgcn_global_load_lds(
      (const __attribute__((address_space(1))) void*)g,
      (__attribute__((address_space(3))) void*)l, 16, 0, 0);
#else
  int lane = threadIdx.x & 63;
  ((int4*)l)[lane] = *(const int4*)g;
#endif
}

// ------------------------- bf16 MFMA GEMM ----------------------------------
// C[M,N] = A[M,K] @ BT[N,K]^T. Tile 128x128, BK=32, 4 waves, 64x64 each.
__global__ __launch_bounds__(256)
void gemm_mfma_kernel(const bf16* __restrict__ A, const bf16* __restrict__ BT,
                      bf16* __restrict__ C, int M, int K, int N) {
  __shared__ bf16 lds[8192];           // 16 KiB: A [0,4096), B [4096,8192)
  const int t = threadIdx.x;
  const int w  = t >> 6, l = t & 63;
  const int wr = w >> 1, wc = w & 1;
  const int lo = l & 15, hi = l >> 4;
  const int m0 = blockIdx.y * 128;
  const int n0 = blockIdx.x * 128;

  f32x4 acc[4][4] = {};

  const int c0 = w * 2, c1 = w * 2 + 1;
  const int kc0 = c0 >> 1, r0 = (c0 & 1) * 64 + l;
  const int kc1 = c1 >> 1, r1 = (c1 & 1) * 64 + l;
  int mr0 = m0 + r0; if (mr0 >= M) mr0 = M - 1;
  int mr1 = m0 + r1; if (mr1 >= M) mr1 = M - 1;
  const bf16* ga0 = A + (size_t)mr0 * K + kc0 * 8;
  const bf16* ga1 = A + (size_t)mr1 * K + kc1 * 8;
  const bf16* gb0 = BT + (size_t)(n0 + r0) * K + kc0 * 8;
  const bf16* gb1 = BT + (size_t)(n0 + r1) * K + kc1 * 8;
  bf16* la0 = &lds[c0 * 512];
  bf16* la1 = &lds[c1 * 512];
  bf16* lb0 = &lds[4096 + c0 * 512];
  bf16* lb1 = &lds[4096 + c1 * 512];

  for (int k0 = 0; k0 < K; k0 += 32) {
    if (k0) __syncthreads();
    glds16(ga0 + k0, la0);
    glds16(ga1 + k0, la1);
    glds16(gb0 + k0, lb0);
    glds16(gb1 + k0, lb1);
    __syncthreads();

    short8 af[4], bfr[4];
#pragma unroll
    for (int f = 0; f < 4; f++) {
      af[f]  = *(const short8*)&lds[hi * 1024 + (wr * 64 + f * 16 + lo) * 8];
      bfr[f] = *(const short8*)&lds[4096 + hi * 1024 + (wc * 64 + f * 16 + lo) * 8];
    }
#pragma unroll
    for (int fm = 0; fm < 4; fm++)
#pragma unroll
      for (int fn = 0; fn < 4; fn++)
        acc[fm][fn] = __builtin_amdgcn_mfma_f32_16x16x32_bf16(af[fm], bfr[fn],
                                                              acc[fm][fn], 0, 0, 0);
  }

#pragma unroll
  for (int fm = 0; fm < 4; fm++) {
#pragma unroll
    for (int r = 0; r < 4; r++) {
      int row = m0 + wr * 64 + fm * 16 + hi * 4 + r;
      if (row < M) {
#pragma unroll
        for (int fn = 0; fn < 4; fn++) {
          int col = n0 + wc * 64 + fn * 16 + lo;
          C[(size_t)row * N + col] = __float2bfloat16(acc[fm][fn][r]);
        }
      }
    }
  }
}

// ------------------------- prep: x -> bf16 ---------------------------------
__global__ void convx_kernel(const float* __restrict__ x, bf16* __restrict__ xb, int n4) {
  int i = blockIdx.x * blockDim.x + threadIdx.x;
  if (i >= n4) return;
  float4 v = ((const float4*)x)[i];
  union { bf16 h[4]; uint2 u; } cv;
  cv.h[0] = __float2bfloat16(v.x); cv.h[1] = __float2bfloat16(v.y);
  cv.h[2] = __float2bfloat16(v.z); cv.h[3] = __float2bfloat16(v.w);
  ((uint2*)xb)[i] = cv.u;
}

// tiled LDS transpose: out[n][k] = bf16(in[k][n]); 4 jobs via blockIdx.z
__global__ __launch_bounds__(256)
void transw_kernel(const float* __restrict__ Wl1, const float* __restrict__ Wr1,
                   const float* __restrict__ Wl2, const float* __restrict__ Wr2,
                   bf16* __restrict__ W1T, bf16* __restrict__ W2T) {
  __shared__ float tile[32][33];
  const int z = blockIdx.z;
  const float* in; bf16* out; int K, Nn;
  if (z == 0)      { in = Wl1; out = W1T;             K = 256; Nn = 512; }
  else if (z == 1) { in = Wr1; out = W1T + 512 * 256; K = 256; Nn = 512; }
  else if (z == 2) { in = Wl2; out = W2T;             K = 512; Nn = 256; }
  else             { in = Wr2; out = W2T + 256 * 512; K = 512; Nn = 256; }
  const int nt = blockIdx.x * 32, kt = blockIdx.y * 32;
  if (nt >= Nn || kt >= K) return;
  const int tx = threadIdx.x & 31, ty = threadIdx.x >> 5;
#pragma unroll
  for (int j = 0; j < 4; j++)
    tile[ty + j * 8][tx] = in[(size_t)(kt + ty + j * 8) * Nn + nt + tx];
  __syncthreads();
#pragma unroll
  for (int j = 0; j < 4; j++)
    out[(size_t)(nt + ty + j * 8) * K + kt + tx] = __float2bfloat16(tile[tx][ty + j * 8]);
}

// ------------------------- edge-attr mean ----------------------------------
__global__ void mean_kernel(const float* __restrict__ eattr, float* __restrict__ sums, int E) {
  int tid = blockIdx.x * blockDim.x + threadIdx.x;
  int stride = gridDim.x * blockDim.x;
  float l0 = 0.f, l1 = 0.f, l2 = 0.f, l3 = 0.f;
  for (int e = tid; e < E; e += stride) {
    float4 v = ((const float4*)eattr)[e];
    l0 += v.x; l1 += v.y; l2 += v.z; l3 += v.w;
  }
#pragma unroll
  for (int o = 1; o < 64; o <<= 1) {
    l0 += __shfl_xor(l0, o); l1 += __shfl_xor(l1, o);
    l2 += __shfl_xor(l2, o); l3 += __shfl_xor(l3, o);
  }
  if ((threadIdx.x & 63) == 0) {
    atomicAdd(&sums[0], l0); atomicAdd(&sums[1], l1);
    atomicAdd(&sums[2], l2); atomicAdd(&sums[3], l3);
  }
}

__global__ void meanw_kernel(const float* __restrict__ sums, float* __restrict__ mean4, float invE) {
  int t = threadIdx.x;
  if (t < 4) mean4[t] = sums[t] * invE;
}

// ------------------------- CSR build ---------------------------------------
__global__ void count_kernel(const int* __restrict__ ei, int* __restrict__ counts, int E, int Etot) {
  int tid = blockIdx.x * blockDim.x + threadIdx.x;
  int stride = gridDim.x * blockDim.x;
  for (int e = tid; e < Etot; e += stride) {
    int dst = (e < E) ? ei[E + e] : (e - E);
    atomicAdd(&counts[dst], 1);
  }
}

__global__ __launch_bounds__(1024)
void scan_kernel(const int* __restrict__ counts, int* __restrict__ offs, int N) {
  __shared__ int wsum[16];
  int tid = threadIdx.x, wid = tid >> 6, lane = tid & 63;
  if (tid == 0) offs[0] = 0;
  int carry = 0;
  for (int base = 0; base < N; base += 1024) {
    int i = base + tid;
    int v = (i < N) ? counts[i] : 0;
    int s = v;
#pragma unroll
    for (int o = 1; o < 64; o <<= 1) {
      int u = __shfl_up(s, o);
      if (lane >= o) s += u;
    }
    if (lane == 63) wsum[wid] = s;
    __syncthreads();
    if (wid == 0) {
      int t2 = (lane < 16) ? wsum[lane] : 0;
#pragma unroll
      for (int o = 1; o < 16; o <<= 1) {
        int u = __shfl_up(t2, o);
        if (lane >= o) t2 += u;
      }
      if (lane < 16) wsum[lane] = t2;
    }
    __syncthreads();
    int pre = (wid > 0) ? wsum[wid - 1] : 0;
    int tot = wsum[15];
    if (i < N) offs[i + 1] = carry + pre + s;
    carry += tot;
    __syncthreads();
  }
}

__global__ void fill_kernel(const int* __restrict__ ei, const int* __restrict__ offs,
                            int* __restrict__ cursor, const float* __restrict__ eattr,
                            const float* __restrict__ mean4, int* __restrict__ srcs,
                            float4* __restrict__ eaC, int E, int Etot) {
  int tid = blockIdx.x * blockDim.x + threadIdx.x;
  int stride = gridDim.x * blockDim.x;
  for (int e = tid; e < Etot; e += stride) {
    int src, dst;
    if (e < E) { src = ei[e]; dst = ei[E + e]; } else { src = e - E; dst = src; }
    int pos = atomicAdd(&cursor[dst], 1);
    int slot = offs[dst] + pos;
    srcs[slot] = src;
    eaC[slot] = (e < E) ? ((const float4*)eattr)[e] : *(const float4*)mean4;
  }
}

// ---------------- layer 1 fused: block/node, contiguous chunks, 8x MLP -----
// xlr: [N][1024] bf16 = [xl(512) | xr(512)]; lane covers 8 ch, head = lane>>4.
__global__ __launch_bounds__(256, 4)
void fused1_kernel(const int* __restrict__ srcs, const float4* __restrict__ eaC,
                   const int* __restrict__ offs, const bf16* __restrict__ xlr,
                   const float* __restrict__ We, const float* __restrict__ att,
                   const float* __restrict__ bias, const float* __restrict__ g,
                   const float* __restrict__ be, bf16* __restrict__ h1) {
  const int v = blockIdx.x;
  const int tid = threadIdx.x;
  const int wave = tid >> 6, lane = tid & 63;
  const int ch = lane * 8;

  float w0[8], w1[8], w2[8], w3[8], aw[8], xr[8];
  *(float4*)&w0[0] = *(const float4*)(We + 0 * HC1 + ch);
  *(float4*)&w0[4] = *(const float4*)(We + 0 * HC1 + ch + 4);
  *(float4*)&w1[0] = *(const float4*)(We + 1 * HC1 + ch);
  *(float4*)&w1[4] = *(const float4*)(We + 1 * HC1 + ch + 4);
  *(float4*)&w2[0] = *(const float4*)(We + 2 * HC1 + ch);
  *(float4*)&w2[4] = *(const float4*)(We + 2 * HC1 + ch + 4);
  *(float4*)&w3[0] = *(const float4*)(We + 3 * HC1 + ch);
  *(float4*)&w3[4] = *(const float4*)(We + 3 * HC1 + ch + 4);
  *(float4*)&aw[0] = *(const float4*)(att + ch);
  *(float4*)&aw[4] = *(const float4*)(att + ch + 4);
  unpack8(*(const short8*)(xlr + (size_t)v * 1024 + 512 + ch), xr);

  const int beg = offs[v], end = offs[v + 1];
  const int len = end - beg;
  const int chunk = (len + 3) >> 2;       // contiguous quarter per wave
  int ib = beg + wave * chunk;
  int ie = ib + chunk;
  if (ib > end) ib = end;
  if (ie > end) ie = end;

  float den = 0.f;
  float acc[8] = {};

  auto edge = [&](short8 q, float4 e) {
    float xa[8]; unpack8(q, xa);
    float p = 0.f;
#pragma unroll
    for (int j = 0; j < 8; j++) {
      float m = xa[j] + xr[j];
      m = fmaf(e.x, w0[j], m); m = fmaf(e.y, w1[j], m);
      m = fmaf(e.z, w2[j], m); m = fmaf(e.w, w3[j], m);
      p = fmaf(fmaxf(m, 0.2f * m), aw[j], p);
    }
    p = red16(p);                       // per-head sum via DPP (VALU pipe)
    float ex = __expf(p);
    den += ex;
#pragma unroll
    for (int j = 0; j < 8; j++) acc[j] = fmaf(ex, xa[j], acc[j]);
  };

  int i = ib;
  for (; i + 8 <= ie; i += 8) {
    int s[8]; float4 e[8]; short8 q[8];
#pragma unroll
    for (int k = 0; k < 8; k++) { s[k] = srcs[i + k]; e[k] = eaC[i + k]; }
#pragma unroll
    for (int k = 0; k < 8; k++) q[k] = *(const short8*)(xlr + (size_t)s[k] * 1024 + ch);
#pragma unroll
    for (int k = 0; k < 8; k++) edge(q[k], e[k]);
  }
  if (i + 4 <= ie) {
    int s[4]; float4 e[4]; short8 q[4];
#pragma unroll
    for (int k = 0; k < 4; k++) { s[k] = srcs[i + k]; e[k] = eaC[i + k]; }
#pragma unroll
    for (int k = 0; k < 4; k++) q[k] = *(const short8*)(xlr + (size_t)s[k] * 1024 + ch);
#pragma unroll
    for (int k = 0; k < 4; k++) edge(q[k], e[k]);
    i += 4;
  }
  for (; i < ie; ++i) {
    int s0 = srcs[i];
    float4 e0 = eaC[i];
    short8 q0 = *(const short8*)(xlr + (size_t)s0 * 1024 + ch);
    edge(q0, e0);
  }

  // ----- cross-wave combine -----
  __shared__ float accs[4][HC1];
  __shared__ float dens[4][4];     // [wave][head]
  __shared__ float2 red[4];
  *(float4*)&accs[wave][ch]     = *(float4*)&acc[0];
  *(float4*)&accs[wave][ch + 4] = *(float4*)&acc[4];
  if ((lane & 15) == 0) dens[wave][lane >> 4] = den;   // per-head partial
  __syncthreads();

  const int c = tid * 2;          // each thread: 2 channels for epilogue
  const int head = c >> 7;        // 128 channels per head
  const float dtot = dens[0][head] + dens[1][head] + dens[2][head] + dens[3][head];
  const float rden = 1.f / (dtot + 1e-16f);
  float2 a0 = *(float2*)&accs[0][c];
  float2 a1 = *(float2*)&accs[1][c];
  float2 a2 = *(float2*)&accs[2][c];
  float2 a3 = *(float2*)&accs[3][c];
  float2 bv = *(const float2*)(bias + c);
  float val0 = (a0.x + a1.x + a2.x + a3.x) * rden + bv.x;
  float val1 = (a0.y + a1.y + a2.y + a3.y) * rden + bv.y;

  float s1 = val0 + val1, s2 = val0 * val0 + val1 * val1;
  s1 = red16(s1); s2 = red16(s2);
  s1 += __shfl_xor(s1, 16); s2 += __shfl_xor(s2, 16);
  s1 += __shfl_xor(s1, 32); s2 += __shfl_xor(s2, 32);
  if (lane == 0) red[wave] = make_float2(s1, s2);
  __syncthreads();
  float ts1 = red[0].x + red[1].x + red[2].x + red[3].x;
  float ts2 = red[0].y + red[1].y + red[2].y + red[3].y;
  float mu  = ts1 * (1.f / HC1);
  float var = ts2 * (1.f / HC1) - mu * mu;
  float rs  = rsqrtf(var + 1e-5f);

  float2 gv = *(const float2*)(g + c);
  float2 ev = *(const float2*)(be + c);
  float ya = (val0 - mu) * rs * gv.x + ev.x;
  float yb = (val1 - mu) * rs * gv.y + ev.y;
  ya = (ya > 0.f) ? ya : expm1f(ya);
  yb = (yb > 0.f) ? yb : expm1f(yb);
  bf162 hv;
  hv.x = __float2bfloat16(ya); hv.y = __float2bfloat16(yb);
  *(bf162*)(h1 + (size_t)v * HC1 + c) = hv;
}

// ---------------- layer 2 fused: block/node, contiguous chunks, 8x MLP -----
// xlr: [N][512] bf16 = [xl(256) | xr(256)]; lane covers 4 ch.
__global__ __launch_bounds__(256, 4)
void fused2_kernel(const int* __restrict__ srcs, const float4* __restrict__ eaC,
                   const int* __restrict__ offs, const bf16* __restrict__ xlr,
                   const float* __restrict__ We, const float* __restrict__ att,
                   const float* __restrict__ bias, const float* __restrict__ g,
                   const float* __restrict__ be, const float* __restrict__ xin,
                   float* __restrict__ out) {
  const int v = blockIdx.x;
  const int tid = threadIdx.x;
  const int wave = tid >> 6, lane = tid & 63;
  const int c0 = lane * 4;

  float w[4][4];
#pragma unroll
  for (int k = 0; k < 4; k++) {
    float4 q = *(const float4*)(We + k * HC2 + c0);
    w[k][0] = q.x; w[k][1] = q.y; w[k][2] = q.z; w[k][3] = q.w;
  }
  float4 atv = *(const float4*)(att + c0);
  float at[4] = {atv.x, atv.y, atv.z, atv.w};
  float xrv[4];
  {
    union { short4 s; bf162 h[2]; } u;
    u.s = *(const short4*)(xlr + (size_t)v * 512 + 256 + c0);
    xrv[0] = __bfloat162float(u.h[0].x); xrv[1] = __bfloat162float(u.h[0].y);
    xrv[2] = __bfloat162float(u.h[1].x); xrv[3] = __bfloat162float(u.h[1].y);
  }

  const int beg = offs[v], end = offs[v + 1];
  const int len = end - beg;
  const int chunk = (len + 3) >> 2;
  int ib = beg + wave * chunk;
  int ie = ib + chunk;
  if (ib > end) ib = end;
  if (ie > end) ie = end;

  float den = 0.f, acc[4] = {0.f, 0.f, 0.f, 0.f};

  auto edge = [&](short4 qs, float4 e) {
    union { short4 s; bf162 h[2]; } u; u.s = qs;
    float xa[4] = {__bfloat162float(u.h[0].x), __bfloat162float(u.h[0].y),
                   __bfloat162float(u.h[1].x), __bfloat162float(u.h[1].y)};
    float p = 0.f;
#pragma unroll
    for (int j = 0; j < 4; j++) {
      float m = xa[j] + xrv[j];
      m = fmaf(e.x, w[0][j], m); m = fmaf(e.y, w[1][j], m);
      m = fmaf(e.z, w[2][j], m); m = fmaf(e.w, w[3][j], m);
      p = fmaf(fmaxf(m, 0.2f * m), at[j], p);
    }
    p = red16(p);
    p += __shfl_xor(p, 16);
    p += __shfl_xor(p, 32);
    float ex = __expf(p);
    den += ex;
#pragma unroll
    for (int j = 0; j < 4; j++) acc[j] = fmaf(ex, xa[j], acc[j]);
  };

  int i = ib;
  for (; i + 8 <= ie; i += 8) {
    int s[8]; float4 e[8]; short4 q[8];
#pragma unroll
    for (int k = 0; k < 8; k++) { s[k] = srcs[i + k]; e[k] = eaC[i + k]; }
#pragma unroll
    for (int k = 0; k < 8; k++) q[k] = *(const short4*)(xlr + (size_t)s[k] * 512 + c0);
#pragma unroll
    for (int k = 0; k < 8; k++) edge(q[k], e[k]);
  }
  if (i + 4 <= ie) {
    int s[4]; float4 e[4]; short4 q[4];
#pragma unroll
    for (int k = 0; k < 4; k++) { s[k] = srcs[i + k]; e[k] = eaC[i + k]; }
#pragma unroll
    for (int k = 0; k < 4; k++) q[k] = *(const short4*)(xlr + (size_t)s[k] * 512 + c0);
#pragma unroll
    for (int k = 0; k < 4; k++) edge(q[k], e[k]);
    i += 4;
  }
  for (; i < ie; ++i) {
    int s0 = srcs[i];
    float4 e0 = eaC[i];
    short4 q0 = *(const short4*)(xlr + (size_t)s0 * 512 + c0);
    edge(q0, e0);
  }

  // ----- cross-wave combine -----
  __shared__ float accs[4][HC2];
  __shared__ float dens[4];
  __shared__ float2 red[4];
  *(float4*)&accs[wave][c0] = *(float4*)&acc[0];
  if (lane == 0) dens[wave] = den;
  __syncthreads();

  const int c = tid;              // each thread: 1 channel
  const float dtot = dens[0] + dens[1] + dens[2] + dens[3];
  const float rden = 1.f / (dtot + 1e-16f);
  float val = (accs[0][c] + accs[1][c] + accs[2][c] + accs[3][c]) * rden + bias[c];

  float s1 = val, s2 = val * val;
  s1 = red16(s1); s2 = red16(s2);
  s1 += __shfl_xor(s1, 16); s2 += __shfl_xor(s2, 16);
  s1 += __shfl_xor(s1, 32); s2 += __shfl_xor(s2, 32);
  if (lane == 0) red[wave] = make_float2(s1, s2);
  __syncthreads();
  float ts1 = red[0].x + red[1].x + red[2].x + red[3].x;
  float ts2 = red[0].y + red[1].y + red[2].y + red[3].y;
  float mu  = ts1 * (1.f / HC2);
  float var = ts2 * (1.f / HC2) - mu * mu;
  float rs  = rsqrtf(var + 1e-5f);
  float y = (val - mu) * rs * g[c] + be[c];
  out[(size_t)v * HC2 + c] = y + xin[(size_t)v * HC2 + c];
}

// ---------------------------------------------------------------------------
extern "C" void kernel_launch(void* const* d_in, const int* in_sizes, int n_in,
                              void* d_out, int out_size, void* d_ws, size_t ws_size,
                              hipStream_t stream) {
  const float* x     = (const float*)d_in[0];
  const int*   ei    = (const int*)d_in[1];
  const float* eattr = (const float*)d_in[2];
  const float* Wl1   = (const float*)d_in[3];
  const float* Wr1   = (const float*)d_in[4];
  const float* We1   = (const float*)d_in[5];
  const float* att1  = (const float*)d_in[6];
  const float* b1    = (const float*)d_in[7];
  const float* g1    = (const float*)d_in[8];
  const float* be1   = (const float*)d_in[9];
  const float* Wl2   = (const float*)d_in[10];
  const float* Wr2   = (const float*)d_in[11];
  const float* We2   = (const float*)d_in[12];
  const float* att2  = (const float*)d_in[13];
  const float* b2    = (const float*)d_in[14];
  const float* g2    = (const float*)d_in[15];
  const float* be2   = (const float*)d_in[16];

  const int N    = in_sizes[0] / D_IN;   // 10000
  const int E    = in_sizes[2] / 4;      // 320000
  const int Etot = E + N;

  char* w = (char*)d_ws;
  auto alloc = [&](size_t bytes) -> void* {
    void* p = (void*)w;
    w += (bytes + 255) & ~(size_t)255;
    return p;
  };
  bf16*   xb    = (bf16*)alloc((size_t)N * D_IN * 2);
  bf16*   W1T   = (bf16*)alloc((size_t)1024 * 256 * 2);
  bf16*   W2T   = (bf16*)alloc((size_t)512 * 512 * 2);
  bf16*   xlr1  = (bf16*)alloc((size_t)N * 1024 * 2);
  bf16*   h1    = (bf16*)alloc((size_t)N * HC1 * 2);
  bf16*   xlr2  = (bf16*)alloc((size_t)N * 512 * 2);
  int*    srcs  = (int*)alloc((size_t)Etot * 4);
  float4* eaC   = (float4*)alloc((size_t)Etot * 16);
  int*    offs  = (int*)alloc((size_t)(N + 1) * 4);
  float*  mean4 = (float*)alloc(64);
  char*   zb    = w;
  int*    counts = (int*)alloc((size_t)N * 4);
  int*    cursor = (int*)alloc((size_t)N * 4);
  float*  sums   = (float*)alloc(64);
  size_t  zbytes = (size_t)(w - zb);

  hipMemsetAsync(zb, 0, zbytes, stream);

  int n4 = N * D_IN / 4;
  convx_kernel<<<(n4 + 255) / 256, 256, 0, stream>>>(x, xb, n4);
  transw_kernel<<<dim3(16, 16, 4), 256, 0, stream>>>(Wl1, Wr1, Wl2, Wr2, W1T, W2T);

  mean_kernel<<<256, 256, 0, stream>>>(eattr, sums, E);
  meanw_kernel<<<1, 64, 0, stream>>>(sums, mean4, 1.f / (float)E);

  count_kernel<<<1024, 256, 0, stream>>>(ei, counts, E, Etot);
  scan_kernel<<<1, 1024, 0, stream>>>(counts, offs, N);
  fill_kernel<<<1024, 256, 0, stream>>>(ei, offs, cursor, eattr, mean4, srcs, eaC, E, Etot);

  dim3 gg1(1024 / 128, (N + 127) / 128);
  gemm_mfma_kernel<<<gg1, 256, 0, stream>>>(xb, W1T, xlr1, N, 256, 1024);

  fused1_kernel<<<N, 256, 0, stream>>>(srcs, eaC, offs, xlr1, We1, att1, b1, g1, be1, h1);

  dim3 gg2(512 / 128, (N + 127) / 128);
  gemm_mfma_kernel<<<gg2, 256, 0, stream>>>(h1, W2T, xlr2, N, 512, 512);

  fused2_kernel<<<N, 256, 0, stream>>>(srcs, eaC, offs, xlr2, We2, att2,
                                       b2, g2, be2, x, (float*)d_out);
}

// Round 9
// 274.274 us; speedup vs baseline: 1.5863x; 1.5863x over previous
//
#include <hip/hip_runtime.h>
#include <hip/hip_bf16.h>

#define HC1 512   // layer-1 heads*channels (4*128)
#define HC2 256   // layer-2 (1*256)
#define D_IN 256

typedef __hip_bfloat16  bf16;
typedef __hip_bfloat162 bf162;
typedef __attribute__((ext_vector_type(8))) short short8;   // 8 bf16 = 4 VGPR
typedef __attribute__((ext_vector_type(4))) float f32x4;

__device__ __forceinline__ void unpack8(short8 q, float* x) {
  union { short8 s; bf162 h[4]; } u; u.s = q;
#pragma unroll
  for (int j = 0; j < 4; j++) {
    x[2 * j]     = __bfloat162float(u.h[j].x);
    x[2 * j + 1] = __bfloat162float(u.h[j].y);
  }
}

// DPP-based partial-wave add on the VALU pipe (no LDS).
// 0xB1 = quad_perm xor1, 0x4E = quad_perm xor2, 0x124 = row_ror:4, 0x128 = row_ror:8.
template <int CTRL>
__device__ __forceinline__ float dppadd(float x) {
  union { float f; int i; } u, v;
  u.f = x;
  v.i = __builtin_amdgcn_update_dpp(0, u.i, CTRL, 0xF, 0xF, true);
  return x + v.f;
}
// sum over each 16-lane group (result in every lane of the group)
__device__ __forceinline__ float red16(float p) {
  p = dppadd<0xB1>(p);
  p = dppadd<0x4E>(p);
  p = dppadd<0x124>(p);
  p = dppadd<0x128>(p);
  return p;
}

// ------------------------- async global->LDS (16B/lane) --------------------
__device__ __forceinline__ void glds16(const bf16* g, bf16* l) {
#if __has_builtin(__builtin_amdgcn_global_load_lds)
  __builtin_amdgcn_global_load_lds(
      (const __attribute__((address_space(1))) void*)g,
      (__attribute__((address_space(3))) void*)l, 16, 0, 0);
#else
  int lane = threadIdx.x & 63;
  ((int4*)l)[lane] = *(const int4*)g;
#endif
}

// ------------------------- bf16 MFMA GEMM ----------------------------------
// C[M,N] = A[M,K] @ BT[N,K]^T. Tile 128x128, BK=32, 4 waves, 64x64 each.
__global__ __launch_bounds__(256)
void gemm_mfma_kernel(const bf16* __restrict__ A, const bf16* __restrict__ BT,
                      bf16* __restrict__ C, int M, int K, int N) {
  __shared__ bf16 lds[8192];           // 16 KiB: A [0,4096), B [4096,8192)
  const int t = threadIdx.x;
  const int w  = t >> 6, l = t & 63;
  const int wr = w >> 1, wc = w & 1;
  const int lo = l & 15, hi = l >> 4;
  const int m0 = blockIdx.y * 128;
  const int n0 = blockIdx.x * 128;

  f32x4 acc[4][4] = {};

  const int c0 = w * 2, c1 = w * 2 + 1;
  const int kc0 = c0 >> 1, r0 = (c0 & 1) * 64 + l;
  const int kc1 = c1 >> 1, r1 = (c1 & 1) * 64 + l;
  int mr0 = m0 + r0; if (mr0 >= M) mr0 = M - 1;
  int mr1 = m0 + r1; if (mr1 >= M) mr1 = M - 1;
  const bf16* ga0 = A + (size_t)mr0 * K + kc0 * 8;
  const bf16* ga1 = A + (size_t)mr1 * K + kc1 * 8;
  const bf16* gb0 = BT + (size_t)(n0 + r0) * K + kc0 * 8;
  const bf16* gb1 = BT + (size_t)(n0 + r1) * K + kc1 * 8;
  bf16* la0 = &lds[c0 * 512];
  bf16* la1 = &lds[c1 * 512];
  bf16* lb0 = &lds[4096 + c0 * 512];
  bf16* lb1 = &lds[4096 + c1 * 512];

  for (int k0 = 0; k0 < K; k0 += 32) {
    if (k0) __syncthreads();
    glds16(ga0 + k0, la0);
    glds16(ga1 + k0, la1);
    glds16(gb0 + k0, lb0);
    glds16(gb1 + k0, lb1);
    __syncthreads();

    short8 af[4], bfr[4];
#pragma unroll
    for (int f = 0; f < 4; f++) {
      af[f]  = *(const short8*)&lds[hi * 1024 + (wr * 64 + f * 16 + lo) * 8];
      bfr[f] = *(const short8*)&lds[4096 + hi * 1024 + (wc * 64 + f * 16 + lo) * 8];
    }
#pragma unroll
    for (int fm = 0; fm < 4; fm++)
#pragma unroll
      for (int fn = 0; fn < 4; fn++)
        acc[fm][fn] = __builtin_amdgcn_mfma_f32_16x16x32_bf16(af[fm], bfr[fn],
                                                              acc[fm][fn], 0, 0, 0);
  }

#pragma unroll
  for (int fm = 0; fm < 4; fm++) {
#pragma unroll
    for (int r = 0; r < 4; r++) {
      int row = m0 + wr * 64 + fm * 16 + hi * 4 + r;
      if (row < M) {
#pragma unroll
        for (int fn = 0; fn < 4; fn++) {
          int col = n0 + wc * 64 + fn * 16 + lo;
          C[(size_t)row * N + col] = __float2bfloat16(acc[fm][fn][r]);
        }
      }
    }
  }
}

// ------------------------- prep: x -> bf16 ---------------------------------
__global__ void convx_kernel(const float* __restrict__ x, bf16* __restrict__ xb, int n4) {
  int i = blockIdx.x * blockDim.x + threadIdx.x;
  if (i >= n4) return;
  float4 v = ((const float4*)x)[i];
  union { bf16 h[4]; uint2 u; } cv;
  cv.h[0] = __float2bfloat16(v.x); cv.h[1] = __float2bfloat16(v.y);
  cv.h[2] = __float2bfloat16(v.z); cv.h[3] = __float2bfloat16(v.w);
  ((uint2*)xb)[i] = cv.u;
}

// tiled LDS transpose: out[n][k] = bf16(in[k][n]); 4 jobs via blockIdx.z
__global__ __launch_bounds__(256)
void transw_kernel(const float* __restrict__ Wl1, const float* __restrict__ Wr1,
                   const float* __restrict__ Wl2, const float* __restrict__ Wr2,
                   bf16* __restrict__ W1T, bf16* __restrict__ W2T) {
  __shared__ float tile[32][33];
  const int z = blockIdx.z;
  const float* in; bf16* out; int K, Nn;
  if (z == 0)      { in = Wl1; out = W1T;             K = 256; Nn = 512; }
  else if (z == 1) { in = Wr1; out = W1T + 512 * 256; K = 256; Nn = 512; }
  else if (z == 2) { in = Wl2; out = W2T;             K = 512; Nn = 256; }
  else             { in = Wr2; out = W2T + 256 * 512; K = 512; Nn = 256; }
  const int nt = blockIdx.x * 32, kt = blockIdx.y * 32;
  if (nt >= Nn || kt >= K) return;
  const int tx = threadIdx.x & 31, ty = threadIdx.x >> 5;
#pragma unroll
  for (int j = 0; j < 4; j++)
    tile[ty + j * 8][tx] = in[(size_t)(kt + ty + j * 8) * Nn + nt + tx];
  __syncthreads();
#pragma unroll
  for (int j = 0; j < 4; j++)
    out[(size_t)(nt + ty + j * 8) * K + kt + tx] = __float2bfloat16(tile[tx][ty + j * 8]);
}

// ------------------------- edge-attr mean ----------------------------------
__global__ void mean_kernel(const float* __restrict__ eattr, float* __restrict__ sums, int E) {
  int tid = blockIdx.x * blockDim.x + threadIdx.x;
  int stride = gridDim.x * blockDim.x;
  float l0 = 0.f, l1 = 0.f, l2 = 0.f, l3 = 0.f;
  for (int e = tid; e < E; e += stride) {
    float4 v = ((const float4*)eattr)[e];
    l0 += v.x; l1 += v.y; l2 += v.z; l3 += v.w;
  }
#pragma unroll
  for (int o = 1; o < 64; o <<= 1) {
    l0 += __shfl_xor(l0, o); l1 += __shfl_xor(l1, o);
    l2 += __shfl_xor(l2, o); l3 += __shfl_xor(l3, o);
  }
  if ((threadIdx.x & 63) == 0) {
    atomicAdd(&sums[0], l0); atomicAdd(&sums[1], l1);
    atomicAdd(&sums[2], l2); atomicAdd(&sums[3], l3);
  }
}

__global__ void meanw_kernel(const float* __restrict__ sums, float* __restrict__ mean4, float invE) {
  int t = threadIdx.x;
  if (t < 4) mean4[t] = sums[t] * invE;
}

// ------------------------- CSR build ---------------------------------------
__global__ void count_kernel(const int* __restrict__ ei, int* __restrict__ counts, int E, int Etot) {
  int tid = blockIdx.x * blockDim.x + threadIdx.x;
  int stride = gridDim.x * blockDim.x;
  for (int e = tid; e < Etot; e += stride) {
    int dst = (e < E) ? ei[E + e] : (e - E);
    atomicAdd(&counts[dst], 1);
  }
}

__global__ __launch_bounds__(1024)
void scan_kernel(const int* __restrict__ counts, int* __restrict__ offs, int N) {
  __shared__ int wsum[16];
  int tid = threadIdx.x, wid = tid >> 6, lane = tid & 63;
  if (tid == 0) offs[0] = 0;
  int carry = 0;
  for (int base = 0; base < N; base += 1024) {
    int i = base + tid;
    int v = (i < N) ? counts[i] : 0;
    int s = v;
#pragma unroll
    for (int o = 1; o < 64; o <<= 1) {
      int u = __shfl_up(s, o);
      if (lane >= o) s += u;
    }
    if (lane == 63) wsum[wid] = s;
    __syncthreads();
    if (wid == 0) {
      int t2 = (lane < 16) ? wsum[lane] : 0;
#pragma unroll
      for (int o = 1; o < 16; o <<= 1) {
        int u = __shfl_up(t2, o);
        if (lane >= o) t2 += u;
      }
      if (lane < 16) wsum[lane] = t2;
    }
    __syncthreads();
    int pre = (wid > 0) ? wsum[wid - 1] : 0;
    int tot = wsum[15];
    if (i < N) offs[i + 1] = carry + pre + s;
    carry += tot;
    __syncthreads();
  }
}

__global__ void fill_kernel(const int* __restrict__ ei, const int* __restrict__ offs,
                            int* __restrict__ cursor, const float* __restrict__ eattr,
                            const float* __restrict__ mean4, int* __restrict__ srcs,
                            float4* __restrict__ eaC, int E, int Etot) {
  int tid = blockIdx.x * blockDim.x + threadIdx.x;
  int stride = gridDim.x * blockDim.x;
  for (int e = tid; e < Etot; e += stride) {
    int src, dst;
    if (e < E) { src = ei[e]; dst = ei[E + e]; } else { src = e - E; dst = src; }
    int pos = atomicAdd(&cursor[dst], 1);
    int slot = offs[dst] + pos;
    srcs[slot] = src;
    eaC[slot] = (e < E) ? ((const float4*)eattr)[e] : *(const float4*)mean4;
  }
}

// ---------------- layer 1 fused: block/node, contiguous chunks, 4x unroll --
// xlr: [N][1024] bf16 = [xl(512) | xr(512)]; lane covers 8 ch, head = lane>>4.
__global__ __launch_bounds__(256, 4)
void fused1_kernel(const int* __restrict__ srcs, const float4* __restrict__ eaC,
                   const int* __restrict__ offs, const bf16* __restrict__ xlr,
                   const float* __restrict__ We, const float* __restrict__ att,
                   const float* __restrict__ bias, const float* __restrict__ g,
                   const float* __restrict__ be, bf16* __restrict__ h1) {
  const int v = blockIdx.x;
  const int tid = threadIdx.x;
  const int wave = tid >> 6, lane = tid & 63;
  const int ch = lane * 8;

  float w0[8], w1[8], w2[8], w3[8], aw[8], xr[8];
  *(float4*)&w0[0] = *(const float4*)(We + 0 * HC1 + ch);
  *(float4*)&w0[4] = *(const float4*)(We + 0 * HC1 + ch + 4);
  *(float4*)&w1[0] = *(const float4*)(We + 1 * HC1 + ch);
  *(float4*)&w1[4] = *(const float4*)(We + 1 * HC1 + ch + 4);
  *(float4*)&w2[0] = *(const float4*)(We + 2 * HC1 + ch);
  *(float4*)&w2[4] = *(const float4*)(We + 2 * HC1 + ch + 4);
  *(float4*)&w3[0] = *(const float4*)(We + 3 * HC1 + ch);
  *(float4*)&w3[4] = *(const float4*)(We + 3 * HC1 + ch + 4);
  *(float4*)&aw[0] = *(const float4*)(att + ch);
  *(float4*)&aw[4] = *(const float4*)(att + ch + 4);
  unpack8(*(const short8*)(xlr + (size_t)v * 1024 + 512 + ch), xr);

  const int beg = offs[v], end = offs[v + 1];
  const int len = end - beg;
  const int chunk = (len + 3) >> 2;       // contiguous quarter per wave
  int ib = beg + wave * chunk;
  int ie = ib + chunk;
  if (ib > end) ib = end;
  if (ie > end) ie = end;

  float den = 0.f;
  float acc[8] = {};

  auto edge = [&](short8 q, float4 e) {
    float xa[8]; unpack8(q, xa);
    float p = 0.f;
#pragma unroll
    for (int j = 0; j < 8; j++) {
      float m = xa[j] + xr[j];
      m = fmaf(e.x, w0[j], m); m = fmaf(e.y, w1[j], m);
      m = fmaf(e.z, w2[j], m); m = fmaf(e.w, w3[j], m);
      p = fmaf(fmaxf(m, 0.2f * m), aw[j], p);
    }
    p = red16(p);                       // per-head sum via DPP (VALU pipe)
    float ex = __expf(p);
    den += ex;
#pragma unroll
    for (int j = 0; j < 8; j++) acc[j] = fmaf(ex, xa[j], acc[j]);
  };

  int i = ib;
  for (; i + 4 <= ie; i += 4) {
    int s0 = srcs[i], s1 = srcs[i + 1], s2 = srcs[i + 2], s3 = srcs[i + 3];
    float4 e0 = eaC[i], e1 = eaC[i + 1], e2 = eaC[i + 2], e3 = eaC[i + 3];
    short8 q0 = *(const short8*)(xlr + (size_t)s0 * 1024 + ch);
    short8 q1 = *(const short8*)(xlr + (size_t)s1 * 1024 + ch);
    short8 q2 = *(const short8*)(xlr + (size_t)s2 * 1024 + ch);
    short8 q3 = *(const short8*)(xlr + (size_t)s3 * 1024 + ch);
    edge(q0, e0); edge(q1, e1); edge(q2, e2); edge(q3, e3);
  }
  for (; i < ie; ++i) {
    int s0 = srcs[i];
    float4 e0 = eaC[i];
    short8 q0 = *(const short8*)(xlr + (size_t)s0 * 1024 + ch);
    edge(q0, e0);
  }

  // ----- cross-wave combine -----
  __shared__ float accs[4][HC1];
  __shared__ float dens[4][4];     // [wave][head]
  __shared__ float2 red[4];
  *(float4*)&accs[wave][ch]     = *(float4*)&acc[0];
  *(float4*)&accs[wave][ch + 4] = *(float4*)&acc[4];
  if ((lane & 15) == 0) dens[wave][lane >> 4] = den;   // per-head partial
  __syncthreads();

  const int c = tid * 2;          // each thread: 2 channels for epilogue
  const int head = c >> 7;        // 128 channels per head
  const float dtot = dens[0][head] + dens[1][head] + dens[2][head] + dens[3][head];
  const float rden = 1.f / (dtot + 1e-16f);
  float2 a0 = *(float2*)&accs[0][c];
  float2 a1 = *(float2*)&accs[1][c];
  float2 a2 = *(float2*)&accs[2][c];
  float2 a3 = *(float2*)&accs[3][c];
  float2 bv = *(const float2*)(bias + c);
  float val0 = (a0.x + a1.x + a2.x + a3.x) * rden + bv.x;
  float val1 = (a0.y + a1.y + a2.y + a3.y) * rden + bv.y;

  float s1 = val0 + val1, s2 = val0 * val0 + val1 * val1;
  s1 = red16(s1); s2 = red16(s2);
  s1 += __shfl_xor(s1, 16); s2 += __shfl_xor(s2, 16);
  s1 += __shfl_xor(s1, 32); s2 += __shfl_xor(s2, 32);
  if (lane == 0) red[wave] = make_float2(s1, s2);
  __syncthreads();
  float ts1 = red[0].x + red[1].x + red[2].x + red[3].x;
  float ts2 = red[0].y + red[1].y + red[2].y + red[3].y;
  float mu  = ts1 * (1.f / HC1);
  float var = ts2 * (1.f / HC1) - mu * mu;
  float rs  = rsqrtf(var + 1e-5f);

  float2 gv = *(const float2*)(g + c);
  float2 ev = *(const float2*)(be + c);
  float ya = (val0 - mu) * rs * gv.x + ev.x;
  float yb = (val1 - mu) * rs * gv.y + ev.y;
  ya = (ya > 0.f) ? ya : expm1f(ya);
  yb = (yb > 0.f) ? yb : expm1f(yb);
  bf162 hv;
  hv.x = __float2bfloat16(ya); hv.y = __float2bfloat16(yb);
  *(bf162*)(h1 + (size_t)v * HC1 + c) = hv;
}

// ---------------- layer 2 fused: block/node, contiguous chunks, 4x unroll --
// xlr: [N][512] bf16 = [xl(256) | xr(256)]; lane covers 4 ch.
__global__ __launch_bounds__(256, 4)
void fused2_kernel(const int* __restrict__ srcs, const float4* __restrict__ eaC,
                   const int* __restrict__ offs, const bf16* __restrict__ xlr,
                   const float* __restrict__ We, const float* __restrict__ att,
                   const float* __restrict__ bias, const float* __restrict__ g,
                   const float* __restrict__ be, const float* __restrict__ xin,
                   float* __restrict__ out) {
  const int v = blockIdx.x;
  const int tid = threadIdx.x;
  const int wave = tid >> 6, lane = tid & 63;
  const int c0 = lane * 4;

  float w[4][4];
#pragma unroll
  for (int k = 0; k < 4; k++) {
    float4 q = *(const float4*)(We + k * HC2 + c0);
    w[k][0] = q.x; w[k][1] = q.y; w[k][2] = q.z; w[k][3] = q.w;
  }
  float4 atv = *(const float4*)(att + c0);
  float at[4] = {atv.x, atv.y, atv.z, atv.w};
  float xrv[4];
  {
    union { short4 s; bf162 h[2]; } u;
    u.s = *(const short4*)(xlr + (size_t)v * 512 + 256 + c0);
    xrv[0] = __bfloat162float(u.h[0].x); xrv[1] = __bfloat162float(u.h[0].y);
    xrv[2] = __bfloat162float(u.h[1].x); xrv[3] = __bfloat162float(u.h[1].y);
  }

  const int beg = offs[v], end = offs[v + 1];
  const int len = end - beg;
  const int chunk = (len + 3) >> 2;
  int ib = beg + wave * chunk;
  int ie = ib + chunk;
  if (ib > end) ib = end;
  if (ie > end) ie = end;

  float den = 0.f, acc[4] = {0.f, 0.f, 0.f, 0.f};

  auto edge = [&](short4 qs, float4 e) {
    union { short4 s; bf162 h[2]; } u; u.s = qs;
    float xa[4] = {__bfloat162float(u.h[0].x), __bfloat162float(u.h[0].y),
                   __bfloat162float(u.h[1].x), __bfloat162float(u.h[1].y)};
    float p = 0.f;
#pragma unroll
    for (int j = 0; j < 4; j++) {
      float m = xa[j] + xrv[j];
      m = fmaf(e.x, w[0][j], m); m = fmaf(e.y, w[1][j], m);
      m = fmaf(e.z, w[2][j], m); m = fmaf(e.w, w[3][j], m);
      p = fmaf(fmaxf(m, 0.2f * m), at[j], p);
    }
    p = red16(p);
    p += __shfl_xor(p, 16);
    p += __shfl_xor(p, 32);
    float ex = __expf(p);
    den += ex;
#pragma unroll
    for (int j = 0; j < 4; j++) acc[j] = fmaf(ex, xa[j], acc[j]);
  };

  int i = ib;
  for (; i + 4 <= ie; i += 4) {
    int s0 = srcs[i], s1 = srcs[i + 1], s2 = srcs[i + 2], s3 = srcs[i + 3];
    float4 e0 = eaC[i], e1 = eaC[i + 1], e2 = eaC[i + 2], e3 = eaC[i + 3];
    short4 q0 = *(const short4*)(xlr + (size_t)s0 * 512 + c0);
    short4 q1 = *(const short4*)(xlr + (size_t)s1 * 512 + c0);
    short4 q2 = *(const short4*)(xlr + (size_t)s2 * 512 + c0);
    short4 q3 = *(const short4*)(xlr + (size_t)s3 * 512 + c0);
    edge(q0, e0); edge(q1, e1); edge(q2, e2); edge(q3, e3);
  }
  for (; i < ie; ++i) {
    int s0 = srcs[i];
    float4 e0 = eaC[i];
    short4 q0 = *(const short4*)(xlr + (size_t)s0 * 512 + c0);
    edge(q0, e0);
  }

  // ----- cross-wave combine -----
  __shared__ float accs[4][HC2];
  __shared__ float dens[4];
  __shared__ float2 red[4];
  *(float4*)&accs[wave][c0] = *(float4*)&acc[0];
  if (lane == 0) dens[wave] = den;
  __syncthreads();

  const int c = tid;              // each thread: 1 channel
  const float dtot = dens[0] + dens[1] + dens[2] + dens[3];
  const float rden = 1.f / (dtot + 1e-16f);
  float val = (accs[0][c] + accs[1][c] + accs[2][c] + accs[3][c]) * rden + bias[c];

  float s1 = val, s2 = val * val;
  s1 = red16(s1); s2 = red16(s2);
  s1 += __shfl_xor(s1, 16); s2 += __shfl_xor(s2, 16);
  s1 += __shfl_xor(s1, 32); s2 += __shfl_xor(s2, 32);
  if (lane == 0) red[wave] = make_float2(s1, s2);
  __syncthreads();
  float ts1 = red[0].x + red[1].x + red[2].x + red[3].x;
  float ts2 = red[0].y + red[1].y + red[2].y + red[3].y;
  float mu  = ts1 * (1.f / HC2);
  float var = ts2 * (1.f / HC2) - mu * mu;
  float rs  = rsqrtf(var + 1e-5f);
  float y = (val - mu) * rs * g[c] + be[c];
  out[(size_t)v * HC2 + c] = y + xin[(size_t)v * HC2 + c];
}

// ---------------------------------------------------------------------------
extern "C" void kernel_launch(void* const* d_in, const int* in_sizes, int n_in,
                              void* d_out, int out_size, void* d_ws, size_t ws_size,
                              hipStream_t stream) {
  const float* x     = (const float*)d_in[0];
  const int*   ei    = (const int*)d_in[1];
  const float* eattr = (const float*)d_in[2];
  const float* Wl1   = (const float*)d_in[3];
  const float* Wr1   = (const float*)d_in[4];
  const float* We1   = (const float*)d_in[5];
  const float* att1  = (const float*)d_in[6];
  const float* b1    = (const float*)d_in[7];
  const float* g1    = (const float*)d_in[8];
  const float* be1   = (const float*)d_in[9];
  const float* Wl2   = (const float*)d_in[10];
  const float* Wr2   = (const float*)d_in[11];
  const float* We2   = (const float*)d_in[12];
  const float* att2  = (const float*)d_in[13];
  const float* b2    = (const float*)d_in[14];
  const float* g2    = (const float*)d_in[15];
  const float* be2   = (const float*)d_in[16];

  const int N    = in_sizes[0] / D_IN;   // 10000
  const int E    = in_sizes[2] / 4;      // 320000
  const int Etot = E + N;

  char* w = (char*)d_ws;
  auto alloc = [&](size_t bytes) -> void* {
    void* p = (void*)w;
    w += (bytes + 255) & ~(size_t)255;
    return p;
  };
  bf16*   xb    = (bf16*)alloc((size_t)N * D_IN * 2);
  bf16*   W1T   = (bf16*)alloc((size_t)1024 * 256 * 2);
  bf16*   W2T   = (bf16*)alloc((size_t)512 * 512 * 2);
  bf16*   xlr1  = (bf16*)alloc((size_t)N * 1024 * 2);
  bf16*   h1    = (bf16*)alloc((size_t)N * HC1 * 2);
  bf16*   xlr2  = (bf16*)alloc((size_t)N * 512 * 2);
  int*    srcs  = (int*)alloc((size_t)Etot * 4);
  float4* eaC   = (float4*)alloc((size_t)Etot * 16);
  int*    offs  = (int*)alloc((size_t)(N + 1) * 4);
  float*  mean4 = (float*)alloc(64);
  char*   zb    = w;
  int*    counts = (int*)alloc((size_t)N * 4);
  int*    cursor = (int*)alloc((size_t)N * 4);
  float*  sums   = (float*)alloc(64);
  size_t  zbytes = (size_t)(w - zb);

  hipMemsetAsync(zb, 0, zbytes, stream);

  int n4 = N * D_IN / 4;
  convx_kernel<<<(n4 + 255) / 256, 256, 0, stream>>>(x, xb, n4);
  transw_kernel<<<dim3(16, 16, 4), 256, 0, stream>>>(Wl1, Wr1, Wl2, Wr2, W1T, W2T);

  mean_kernel<<<256, 256, 0, stream>>>(eattr, sums, E);
  meanw_kernel<<<1, 64, 0, stream>>>(sums, mean4, 1.f / (float)E);

  count_kernel<<<1024, 256, 0, stream>>>(ei, counts, E, Etot);
  scan_kernel<<<1, 1024, 0, stream>>>(counts, offs, N);
  fill_kernel<<<1024, 256, 0, stream>>>(ei, offs, cursor, eattr, mean4, srcs, eaC, E, Etot);

  dim3 gg1(1024 / 128, (N + 127) / 128);
  gemm_mfma_kernel<<<gg1, 256, 0, stream>>>(xb, W1T, xlr1, N, 256, 1024);

  fused1_kernel<<<N, 256, 0, stream>>>(srcs, eaC, offs, xlr1, We1, att1, b1, g1, be1, h1);

  dim3 gg2(512 / 128, (N + 127) / 128);
  gemm_mfma_kernel<<<gg2, 256, 0, stream>>>(h1, W2T, xlr2, N, 512, 512);

  fused2_kernel<<<N, 256, 0, stream>>>(srcs, eaC, offs, xlr2, We2, att2,
                                       b2, g2, be2, x, (float*)d_out);
}